// Round 2
// baseline (447.859 us; speedup 1.0000x reference)
//
#include <hip/hip_runtime.h>
#include <cstdint>

#define B_ 4
#define S_ 4096
#define D_ 512
#define M_ (B_*S_)   // 16384 rows

typedef _Float16 f16;
typedef _Float16 f16x8 __attribute__((ext_vector_type(8)));
typedef float    f32x4 __attribute__((ext_vector_type(4)));

typedef __attribute__((address_space(1))) void* as1p;
typedef __attribute__((address_space(3))) void* as3p;

__device__ __forceinline__ void gl2lds16(const void* g, void* l) {
    // async global->LDS, 16B/lane; LDS dest = wave-uniform base + lane*16
    __builtin_amdgcn_global_load_lds((as1p)g, (as3p)l, 16, 0, 0);
}

// ---------------- prep: cast xs->f16 + per-block column partial sums ----------------
// grid 256 blocks x 256 thr; block = 64 rows. partialXS[blk][512].
__global__ __launch_bounds__(256) void prep_kernel(const float* __restrict__ xs,
    f16* __restrict__ xs_h, float* __restrict__ partialXS)
{
    __shared__ float red[4][512];
    const int t = threadIdx.x, blk = blockIdx.x;
    const int w = t >> 6, l = t & 63;
    const int col = l * 8;
    float acc[8] = {0,0,0,0,0,0,0,0};
    for (int c = 0; c < 16; c++) {
        int row = blk*64 + c*4 + w;
        const float4* p = (const float4*)(xs + (size_t)row*512 + col);
        float4 a = p[0], b = p[1];
        f16x8 o;
        o[0]=(f16)a.x; o[1]=(f16)a.y; o[2]=(f16)a.z; o[3]=(f16)a.w;
        o[4]=(f16)b.x; o[5]=(f16)b.y; o[6]=(f16)b.z; o[7]=(f16)b.w;
        *(f16x8*)(xs_h + (size_t)row*512 + col) = o;
        acc[0]+=a.x; acc[1]+=a.y; acc[2]+=a.z; acc[3]+=a.w;
        acc[4]+=b.x; acc[5]+=b.y; acc[6]+=b.z; acc[7]+=b.w;
    }
    #pragma unroll
    for (int q = 0; q < 8; q++) red[w][col+q] = acc[q];
    __syncthreads();
    #pragma unroll
    for (int k = 0; k < 2; k++) {
        int c = t + k*256;
        partialXS[(size_t)blk*512 + c] = red[0][c]+red[1][c]+red[2][c]+red[3][c];
    }
}

// ---------------- B kernel: xsSum -> kSum -> h, c1 (4 blocks, one per batch) ----------------
// kSum[d] = Wk[d,:].xsSum + 4096*bk[d];  h[j] = sum_d Wq[d,j]*kSum[d];  c1 = bq.kSum
__global__ __launch_bounds__(256) void bk_kernel(const float* __restrict__ partialXS,
    const float* __restrict__ Wk, const float* __restrict__ bkv,
    const float* __restrict__ Wq, const float* __restrict__ bq,
    float* __restrict__ hG, float* __restrict__ c1G)
{
    __shared__ float sx[512];
    __shared__ float ks[512];
    const int b = blockIdx.x, t = threadIdx.x;
    #pragma unroll
    for (int k = 0; k < 2; k++) {
        int c = t + k*256;
        float s = 0.f;
        for (int p = 0; p < 64; p++) s += partialXS[(size_t)(b*64+p)*512 + c];
        sx[c] = s;
    }
    __syncthreads();
    #pragma unroll
    for (int k = 0; k < 2; k++) {
        int d = t + k*256;
        const float4* wr = (const float4*)(Wk + (size_t)d*512);
        float s = 0.f;
        #pragma unroll 4
        for (int j = 0; j < 128; j++) {
            float4 v = wr[j];
            s += v.x*sx[j*4] + v.y*sx[j*4+1] + v.z*sx[j*4+2] + v.w*sx[j*4+3];
        }
        ks[d] = s + 4096.0f*bkv[d];
    }
    __syncthreads();
    #pragma unroll
    for (int k = 0; k < 2; k++) {
        int j = t + k*256;
        float s = 0.f;
        #pragma unroll 4
        for (int d = 0; d < 512; d++) s += Wq[(size_t)d*512 + j]*ks[d];
        hG[b*512 + j] = s;
    }
    if (t < 64) {
        float s = 0.f;
        #pragma unroll
        for (int q = 0; q < 8; q++) s += bq[t*8+q]*ks[t*8+q];
        for (int m = 1; m < 64; m <<= 1) s += __shfl_xor(s, m);
        if (t == 0) c1G[b] = s;
    }
}

// ---------------- Wvl = Wl @ Wv (fp32, f16 out) + bvl = Wl @ bv ----------------
__global__ __launch_bounds__(256) void wvl_kernel(const float* __restrict__ Wl,
    const float* __restrict__ Wv, const float* __restrict__ bv,
    f16* __restrict__ WvlH, float* __restrict__ bvlG)
{
    __shared__ float As[128][33];
    __shared__ float Bs[32][132];
    const int bx = blockIdx.x, by = blockIdx.y, t = threadIdx.x;
    const int tx = t & 15, ty = t >> 4;
    float acc[8][8] = {};
    for (int k0 = 0; k0 < 512; k0 += 32) {
        __syncthreads();
        #pragma unroll
        for (int it = 0; it < 4; it++) {
            int s = it*256 + t;
            int i = s >> 3, m4 = (s & 7)*4;
            float4 v = *(const float4*)(Wl + (size_t)(bx*128+i)*512 + k0 + m4);
            As[i][m4]=v.x; As[i][m4+1]=v.y; As[i][m4+2]=v.z; As[i][m4+3]=v.w;
        }
        #pragma unroll
        for (int it = 0; it < 4; it++) {
            int s = it*256 + t;
            int m = s >> 5, j4 = (s & 31)*4;
            float4 v = *(const float4*)(Wv + (size_t)(k0+m)*512 + by*128 + j4);
            Bs[m][j4]=v.x; Bs[m][j4+1]=v.y; Bs[m][j4+2]=v.z; Bs[m][j4+3]=v.w;
        }
        __syncthreads();
        for (int m = 0; m < 32; m++) {
            float a[8], bb[8];
            #pragma unroll
            for (int r = 0; r < 8; r++) a[r] = As[ty*8+r][m];
            #pragma unroll
            for (int c = 0; c < 8; c++) bb[c] = Bs[m][tx*8+c];
            #pragma unroll
            for (int r = 0; r < 8; r++)
                #pragma unroll
                for (int c = 0; c < 8; c++) acc[r][c] += a[r]*bb[c];
        }
    }
    for (int r = 0; r < 8; r++) {
        int i = bx*128 + ty*8 + r;
        #pragma unroll
        for (int c = 0; c < 8; c++)
            WvlH[(size_t)i*512 + by*128 + tx*8 + c] = (f16)acc[r][c];
    }
    if (by == 0 && t < 128) {
        int i = bx*128 + t;
        const float4* wr = (const float4*)(Wl + (size_t)i*512);
        float s = 0.f;
        #pragma unroll 4
        for (int j = 0; j < 128; j++) {
            float4 v = wr[j];
            s += v.x*bv[j*4] + v.y*bv[j*4+1] + v.z*bv[j*4+2] + v.w*bv[j*4+3];
        }
        bvlG[i] = s;
    }
}

// ---------------- z kernel: invZ = 1/(4096 + (xs.h + c1)/512); partials of y, S0 ----------------
// grid 256 blocks; block = 64 rows, wave per row x16 iters.
__global__ __launch_bounds__(256) void z_kernel(const f16* __restrict__ xs_h,
    const float* __restrict__ hG, const float* __restrict__ c1G,
    float* __restrict__ partialY, float* __restrict__ partialS0)
{
    __shared__ float hs[512];
    __shared__ float yred[4][512];
    __shared__ float s0red[4];
    const int blk = blockIdx.x, t = threadIdx.x;
    const int b = blk >> 6, w = t >> 6, l = t & 63;
    hs[t] = hG[b*512 + t]; hs[t+256] = hG[b*512 + t + 256];
    __syncthreads();
    const float c1 = c1G[b];
    float hx[8];
    #pragma unroll
    for (int q = 0; q < 8; q++) hx[q] = hs[l*8+q];
    float yacc[8] = {0,0,0,0,0,0,0,0};
    float s0acc = 0.f;
    for (int it = 0; it < 16; it++) {
        int row = blk*64 + w*16 + it;
        f16x8 v = *(const f16x8*)(xs_h + (size_t)row*512 + l*8);
        float xf[8];
        #pragma unroll
        for (int q = 0; q < 8; q++) xf[q] = (float)v[q];
        float d = 0.f;
        #pragma unroll
        for (int q = 0; q < 8; q++) d += xf[q]*hx[q];
        for (int m = 1; m < 64; m <<= 1) d += __shfl_xor(d, m);
        float z  = 4096.0f + (d + c1)*(1.0f/512.0f);
        float iv = 1.0f/z;
        s0acc += iv;
        #pragma unroll
        for (int q = 0; q < 8; q++) yacc[q] += iv*xf[q];
    }
    #pragma unroll
    for (int q = 0; q < 8; q++) yred[w][l*8+q] = yacc[q];
    if (l == 0) s0red[w] = s0acc;
    __syncthreads();
    #pragma unroll
    for (int k = 0; k < 2; k++) {
        int c = t + k*256;
        partialY[(size_t)blk*512 + c] = yred[0][c]+yred[1][c]+yred[2][c]+yred[3][c];
    }
    if (t == 0) partialS0[blk] = s0red[0]+s0red[1]+s0red[2]+s0red[3];
}

// ---------------- C kernel: y,S0 -> qw -> u, c2 (4 blocks) ----------------
__global__ __launch_bounds__(256) void ck_kernel(const float* __restrict__ partialY,
    const float* __restrict__ partialS0,
    const float* __restrict__ Wq, const float* __restrict__ bq,
    const float* __restrict__ Wk, const float* __restrict__ bkv,
    float* __restrict__ uG, float* __restrict__ c2G, float* __restrict__ S0G)
{
    __shared__ float y[512];
    __shared__ float qw[512];
    __shared__ float s0sh;
    const int b = blockIdx.x, t = threadIdx.x;
    #pragma unroll
    for (int k = 0; k < 2; k++) {
        int c = t + k*256;
        float s = 0.f;
        for (int p = 0; p < 64; p++) s += partialY[(size_t)(b*64+p)*512 + c];
        y[c] = s;
    }
    if (t < 64) {
        float s = partialS0[b*64 + t];
        for (int m = 1; m < 64; m <<= 1) s += __shfl_xor(s, m);
        if (t == 0) s0sh = s;
    }
    __syncthreads();
    const float S0 = s0sh;
    #pragma unroll
    for (int k = 0; k < 2; k++) {
        int d = t + k*256;
        const float4* wr = (const float4*)(Wq + (size_t)d*512);
        float s = 0.f;
        #pragma unroll 4
        for (int j = 0; j < 128; j++) {
            float4 v = wr[j];
            s += v.x*y[j*4] + v.y*y[j*4+1] + v.z*y[j*4+2] + v.w*y[j*4+3];
        }
        qw[d] = s + S0*bq[d];
    }
    __syncthreads();
    #pragma unroll
    for (int k = 0; k < 2; k++) {
        int j = t + k*256;
        float s = 0.f;
        #pragma unroll 4
        for (int d = 0; d < 512; d++) s += Wk[(size_t)d*512 + j]*qw[d];
        uG[b*512 + j] = s;
    }
    if (t < 64) {
        float s = 0.f;
        #pragma unroll
        for (int q = 0; q < 8; q++) s += bkv[t*8+q]*qw[t*8+q];
        for (int m = 1; m < 64; m <<= 1) s += __shfl_xor(s, m);
        if (t == 0) { c2G[b] = s; S0G[b] = S0; }
    }
}

// ---------------- rs kernel: rs[s] = S0 + (xs.u + c2)/512 ----------------
__global__ __launch_bounds__(256) void rs_kernel(const f16* __restrict__ xs_h,
    const float* __restrict__ uG, const float* __restrict__ c2G, const float* __restrict__ S0G,
    float* __restrict__ rsG)
{
    __shared__ float us[512];
    const int blk = blockIdx.x, t = threadIdx.x;
    const int b = blk >> 6, w = t >> 6, l = t & 63;
    us[t] = uG[b*512 + t]; us[t+256] = uG[b*512 + t + 256];
    __syncthreads();
    const float c2 = c2G[b], S0 = S0G[b];
    float ux[8];
    #pragma unroll
    for (int q = 0; q < 8; q++) ux[q] = us[l*8+q];
    for (int it = 0; it < 16; it++) {
        int row = blk*64 + w*16 + it;
        f16x8 v = *(const f16x8*)(xs_h + (size_t)row*512 + l*8);
        float d = 0.f;
        #pragma unroll
        for (int q = 0; q < 8; q++) d += (float)v[q]*ux[q];
        for (int m = 1; m < 64; m <<= 1) d += __shfl_xor(d, m);
        if (l == 0) rsG[row] = S0 + (d + c2)*(1.0f/512.0f);
    }
}

// ---------------- VL GEMM (f16 MFMA) + fused rs/tanh epilogue -> out ----------------
// out[r,c] = tanh(rs[r]*(xs@Wvl^T + bvl)[r,c] + bl[c]);  grid (128,4), 128x128 tile
__global__ __launch_bounds__(256, 2) void vl_gemm(const f16* __restrict__ A,
    const f16* __restrict__ Bt, const float* __restrict__ bvlG,
    const float* __restrict__ blG, const float* __restrict__ rsG,
    float* __restrict__ out)
{
    constexpr int K = 512;
    __shared__ f16 lA[128*32];
    __shared__ f16 lB[128*32];
    const int t = threadIdx.x;
    const int m0 = blockIdx.x*128, n0 = blockIdx.y*128;
    const int lane = t & 63, wid = t >> 6;
    const int wm = (wid & 1) << 6, wn = (wid >> 1) << 6;
    const int srow = t >> 2, skb = (t & 3) << 4;
    const long aoff0 = (long)(m0 + srow)*(K*2) + skb;
    const long aoff1 = aoff0 + 64L*(K*2);
    const long boff0 = (long)(n0 + srow)*(K*2) + skb;
    const long boff1 = boff0 + 64L*(K*2);
    char* ldsA = (char*)lA;
    char* ldsB = (char*)lB;
    const unsigned wbase = (unsigned)wid << 10;
    const char* Ab = (const char*)A;
    const char* Bb = (const char*)Bt;

    f32x4 acc[4][4] = {};
    const int ael = (wm + (lane & 15))*32 + ((lane >> 4) << 3);
    const int bel = (wn + (lane & 15))*32 + ((lane >> 4) << 3);

    for (int k0 = 0; k0 < K; k0 += 32) {
        __syncthreads();
        const long kb = (long)k0*2;
        gl2lds16(Ab + aoff0 + kb, ldsA + wbase);
        gl2lds16(Ab + aoff1 + kb, ldsA + 4096 + wbase);
        gl2lds16(Bb + boff0 + kb, ldsB + wbase);
        gl2lds16(Bb + boff1 + kb, ldsB + 4096 + wbase);
        __syncthreads();
        f16x8 af[4], bf[4];
        #pragma unroll
        for (int i = 0; i < 4; i++) af[i] = *(const f16x8*)(lA + ael + i*512);
        #pragma unroll
        for (int j = 0; j < 4; j++) bf[j] = *(const f16x8*)(lB + bel + j*512);
        #pragma unroll
        for (int i = 0; i < 4; i++)
            #pragma unroll
            for (int j = 0; j < 4; j++)
                acc[i][j] = __builtin_amdgcn_mfma_f32_16x16x32_f16(af[i], bf[j], acc[i][j], 0, 0, 0);
    }

    const int crb = m0 + wm + ((lane >> 4) << 2);
    const int ccb = n0 + wn + (lane & 15);
    #pragma unroll
    for (int i = 0; i < 4; i++) {
        float rsv[4];
        #pragma unroll
        for (int r = 0; r < 4; r++) rsv[r] = rsG[crb + i*16 + r];
        #pragma unroll
        for (int j = 0; j < 4; j++) {
            int c = ccb + j*16;
            float bb = bvlG[c], bo = blG[c];
            #pragma unroll
            for (int r = 0; r < 4; r++) {
                float yv = rsv[r]*(acc[i][j][r] + bb) + bo;
                float e2 = __expf(2.0f*yv);
                out[(size_t)(crb + i*16 + r)*512 + c] = 1.0f - 2.0f/(e2 + 1.0f);
            }
        }
    }
}

extern "C" void kernel_launch(void* const* d_in, const int* in_sizes, int n_in,
                              void* d_out, int out_size, void* d_ws, size_t ws_size,
                              hipStream_t stream)
{
    const float* xs = (const float*)d_in[0];
    const float* Wk = (const float*)d_in[1];
    const float* bk = (const float*)d_in[2];
    const float* Wq = (const float*)d_in[3];
    const float* bq = (const float*)d_in[4];
    const float* Wv = (const float*)d_in[5];
    const float* bv = (const float*)d_in[6];
    const float* Wl = (const float*)d_in[7];
    const float* bl = (const float*)d_in[8];
    float* out = (float*)d_out;

    char* w = (char*)d_ws;
    f16*   xs_h      = (f16*)w;    w += (size_t)M_*D_*2;      // 16.8 MB
    f16*   WvlH      = (f16*)w;    w += (size_t)D_*D_*2;      // 0.5 MB
    float* partialXS = (float*)w;  w += (size_t)256*512*4;    // 512 KB
    float* partialY  = (float*)w;  w += (size_t)256*512*4;    // 512 KB
    float* partialS0 = (float*)w;  w += 256*4;
    float* hG        = (float*)w;  w += B_*512*4;
    float* c1G       = (float*)w;  w += B_*4;
    float* uG        = (float*)w;  w += B_*512*4;
    float* c2G       = (float*)w;  w += B_*4;
    float* S0G       = (float*)w;  w += B_*4;
    float* bvlG      = (float*)w;  w += 512*4;
    float* rsG       = (float*)w;  w += (size_t)M_*4;         // 64 KB
    if ((size_t)(w - (char*)d_ws) > ws_size) return;          // fail loudly

    prep_kernel<<<256, 256, 0, stream>>>(xs, xs_h, partialXS);
    bk_kernel<<<4, 256, 0, stream>>>(partialXS, Wk, bk, Wq, bq, hG, c1G);
    wvl_kernel<<<dim3(4,4), 256, 0, stream>>>(Wl, Wv, bv, WvlH, bvlG);
    z_kernel<<<256, 256, 0, stream>>>(xs_h, hG, c1G, partialY, partialS0);
    ck_kernel<<<4, 256, 0, stream>>>(partialY, partialS0, Wq, bq, Wk, bk, uG, c2G, S0G);
    rs_kernel<<<256, 256, 0, stream>>>(xs_h, uG, c2G, S0G, rsG);
    vl_gemm<<<dim3(128,4), 256, 0, stream>>>(xs_h, WvlH, bvlG, bl, rsG, out);
}

// Round 3
// 199.648 us; speedup vs baseline: 2.2432x; 2.2432x over previous
//
#include <hip/hip_runtime.h>
#include <cstdint>

#define B_ 4
#define S_ 4096
#define D_ 512
#define M_ (B_*S_)   // 16384 rows

typedef _Float16 f16;
typedef _Float16 f16x8 __attribute__((ext_vector_type(8)));
typedef _Float16 f16x4 __attribute__((ext_vector_type(4)));
typedef float    f32x4 __attribute__((ext_vector_type(4)));

typedef __attribute__((address_space(1))) void* as1p;
typedef __attribute__((address_space(3))) void* as3p;

__device__ __forceinline__ void gl2lds16(const void* g, void* l) {
    __builtin_amdgcn_global_load_lds((as1p)g, (as3p)l, 16, 0, 0);
}

// ---------------- prep: cast xs->f16 + per-block column partial sums ----------------
__global__ __launch_bounds__(256) void prep_kernel(const float* __restrict__ xs,
    f16* __restrict__ xs_h, float* __restrict__ partialXS)
{
    __shared__ float red[4][512];
    const int t = threadIdx.x, blk = blockIdx.x;
    const int w = t >> 6, l = t & 63;
    const int col = l * 8;
    float acc[8] = {0,0,0,0,0,0,0,0};
    for (int c = 0; c < 16; c++) {
        int row = blk*64 + c*4 + w;
        const float4* p = (const float4*)(xs + (size_t)row*512 + col);
        float4 a = p[0], b = p[1];
        f16x8 o;
        o[0]=(f16)a.x; o[1]=(f16)a.y; o[2]=(f16)a.z; o[3]=(f16)a.w;
        o[4]=(f16)b.x; o[5]=(f16)b.y; o[6]=(f16)b.z; o[7]=(f16)b.w;
        *(f16x8*)(xs_h + (size_t)row*512 + col) = o;
        acc[0]+=a.x; acc[1]+=a.y; acc[2]+=a.z; acc[3]+=a.w;
        acc[4]+=b.x; acc[5]+=b.y; acc[6]+=b.z; acc[7]+=b.w;
    }
    #pragma unroll
    for (int q = 0; q < 8; q++) red[w][col+q] = acc[q];
    __syncthreads();
    #pragma unroll
    for (int k = 0; k < 2; k++) {
        int c = t + k*256;
        partialXS[(size_t)blk*512 + c] = red[0][c]+red[1][c]+red[2][c]+red[3][c];
    }
}

// ---------------- red: outv[b][c] = sum_p part[(b*64+p)*512+c]; optional S0 ----------------
// grid 8 = 4 batches x 2 column halves
__global__ __launch_bounds__(256) void red_kernel(const float* __restrict__ part,
    const float* __restrict__ partS0, float* __restrict__ outv, float* __restrict__ S0G)
{
    const int b = blockIdx.x >> 1, half = blockIdx.x & 1;
    const int t = threadIdx.x;
    const int c = half*256 + t;
    const float* p = part + (size_t)b*64*512 + c;
    float s = 0.f;
    #pragma unroll 16
    for (int q = 0; q < 64; q++) s += p[(size_t)q*512];
    outv[b*512 + c] = s;
    if (partS0 != nullptr && half == 0 && t < 64) {
        float v = partS0[b*64 + t];
        #pragma unroll
        for (int m = 1; m < 64; m <<= 1) v += __shfl_xor(v, m);
        if (t == 0) S0G[b] = v;
    }
}

// ---------------- mva: oput[b][d] = W[d,:].vin[b] + beta_b*bias[d] ----------------
// beta_b = betaG ? betaG[b] : 4096.  grid 32 x 16 rows; wave = 4 rows, 64-lane K split.
__global__ __launch_bounds__(256) void mva_kernel(const float* __restrict__ W,
    const float* __restrict__ vin, const float* __restrict__ bias,
    const float* __restrict__ betaG, float* __restrict__ oput)
{
    const int t = threadIdx.x, w = t >> 6, l = t & 63;
    float vb[4][8];
    #pragma unroll
    for (int b = 0; b < 4; b++) {
        float4 p0 = *(const float4*)(vin + b*512 + l*8);
        float4 p1 = *(const float4*)(vin + b*512 + l*8 + 4);
        vb[b][0]=p0.x; vb[b][1]=p0.y; vb[b][2]=p0.z; vb[b][3]=p0.w;
        vb[b][4]=p1.x; vb[b][5]=p1.y; vb[b][6]=p1.z; vb[b][7]=p1.w;
    }
    const int r0 = blockIdx.x*16 + w*4;
    float res[4][4];
    #pragma unroll
    for (int r = 0; r < 4; r++) {
        const float4* wr = (const float4*)(W + (size_t)(r0+r)*512 + l*8);
        float4 a = wr[0], c = wr[1];
        float wv[8] = {a.x,a.y,a.z,a.w,c.x,c.y,c.z,c.w};
        #pragma unroll
        for (int b = 0; b < 4; b++) {
            float s = 0.f;
            #pragma unroll
            for (int q = 0; q < 8; q++) s += wv[q]*vb[b][q];
            res[r][b] = s;
        }
    }
    #pragma unroll
    for (int r = 0; r < 4; r++)
        #pragma unroll
        for (int b = 0; b < 4; b++)
            #pragma unroll
            for (int m = 1; m < 64; m <<= 1) res[r][b] += __shfl_xor(res[r][b], m);
    if (l < 4) {
        const float beta = betaG ? betaG[l] : 4096.0f;
        #pragma unroll
        for (int r = 0; r < 4; r++)
            oput[l*512 + r0 + r] = res[r][l] + beta*bias[r0 + r];
    }
}

// ---------------- mvb: oput[b][j] = sum_d W[d][j]*vin[b][d]; block0: cG[b]=bias.vin[b] ----------------
// grid 8 x 64 cols; lanes = 64 consecutive j (coalesced), waves split d 4-way.
__global__ __launch_bounds__(256) void mvb_kernel(const float* __restrict__ W,
    const float* __restrict__ vin, const float* __restrict__ bias,
    float* __restrict__ oput, float* __restrict__ cG)
{
    __shared__ float vsh[4*512];
    __shared__ float red[4][256];
    __shared__ float csc[256][4];
    const int t = threadIdx.x, w = t >> 6, l = t & 63;
    const int j0 = blockIdx.x * 64;
    {
        const float4* src = (const float4*)vin;
        ((float4*)vsh)[t]       = src[t];
        ((float4*)vsh)[t + 256] = src[t + 256];
    }
    __syncthreads();
    float acc[4] = {0.f,0.f,0.f,0.f};
    const int j = j0 + l;
    const float* wp = W + (size_t)(w*128)*512 + j;
    #pragma unroll 32
    for (int d = 0; d < 128; d++) {
        float wv = wp[(size_t)d*512];
        int dd = w*128 + d;
        acc[0] += wv * vsh[dd];
        acc[1] += wv * vsh[512 + dd];
        acc[2] += wv * vsh[1024 + dd];
        acc[3] += wv * vsh[1536 + dd];
    }
    #pragma unroll
    for (int b = 0; b < 4; b++) red[w][(b<<6) + l] = acc[b];
    __syncthreads();
    if (w == 0) {
        #pragma unroll
        for (int b = 0; b < 4; b++) {
            int idx = (b<<6) + l;
            oput[b*512 + j] = red[0][idx]+red[1][idx]+red[2][idx]+red[3][idx];
        }
    }
    if (blockIdx.x == 0) {
        float b0 = bias[t], b1 = bias[t + 256];
        #pragma unroll
        for (int b = 0; b < 4; b++)
            csc[t][b] = b0*vsh[b*512 + t] + b1*vsh[b*512 + t + 256];
        __syncthreads();
        for (int s2 = 128; s2 > 0; s2 >>= 1) {
            if (t < s2)
                #pragma unroll
                for (int b = 0; b < 4; b++) csc[t][b] += csc[t + s2][b];
            __syncthreads();
        }
        if (t < 4) cG[t] = csc[0][t];
    }
}

// ---------------- wvl: Wvl = Wl @ Wv (f16 out, N-K layout for gemm_bt) + bvl = Wl @ bv ----------------
// grid (8,8), 64x64 tile, 4x4/thread, transposed-A LDS so inner = 2x ds_read_b128.
__global__ __launch_bounds__(256) void wvl_kernel(const float* __restrict__ Wl,
    const float* __restrict__ Wv, const float* __restrict__ bv,
    f16* __restrict__ WvlH, float* __restrict__ bvlG)
{
    __shared__ float At[32][68];
    __shared__ float Bs[32][68];
    const int t = threadIdx.x;
    const int i0 = blockIdx.x*64, j0 = blockIdx.y*64;
    const int tx = t & 15, ty = t >> 4;
    float acc[4][4] = {};
    for (int k0 = 0; k0 < 512; k0 += 32) {
        __syncthreads();
        {
            int i = t >> 2, kq = (t & 3) * 8;
            float4 a0 = *(const float4*)(Wl + (size_t)(i0+i)*512 + k0 + kq);
            float4 a1 = *(const float4*)(Wl + (size_t)(i0+i)*512 + k0 + kq + 4);
            At[kq+0][i]=a0.x; At[kq+1][i]=a0.y; At[kq+2][i]=a0.z; At[kq+3][i]=a0.w;
            At[kq+4][i]=a1.x; At[kq+5][i]=a1.y; At[kq+6][i]=a1.z; At[kq+7][i]=a1.w;
            int m = t >> 3, jq = (t & 7) * 8;
            float4 b0 = *(const float4*)(Wv + (size_t)(k0+m)*512 + j0 + jq);
            float4 b1 = *(const float4*)(Wv + (size_t)(k0+m)*512 + j0 + jq + 4);
            *(float4*)&Bs[m][jq]   = b0;
            *(float4*)&Bs[m][jq+4] = b1;
        }
        __syncthreads();
        #pragma unroll
        for (int m = 0; m < 32; m++) {
            float4 av = *(const float4*)&At[m][ty*4];
            float4 bw = *(const float4*)&Bs[m][tx*4];
            float ar[4] = {av.x,av.y,av.z,av.w};
            float br[4] = {bw.x,bw.y,bw.z,bw.w};
            #pragma unroll
            for (int r = 0; r < 4; r++)
                #pragma unroll
                for (int c = 0; c < 4; c++) acc[r][c] += ar[r]*br[c];
        }
    }
    #pragma unroll
    for (int r = 0; r < 4; r++) {
        f16x4 o;
        #pragma unroll
        for (int c = 0; c < 4; c++) o[c] = (f16)acc[r][c];
        *(f16x4*)(WvlH + (size_t)(i0+ty*4+r)*512 + j0 + tx*4) = o;
    }
    if (blockIdx.y == 0) {
        int r = t >> 2, part = t & 3;
        const float4* wr = (const float4*)(Wl + (size_t)(i0+r)*512 + part*128);
        const float4* bp = (const float4*)(bv + part*128);
        float s = 0.f;
        #pragma unroll 8
        for (int q = 0; q < 32; q++) {
            float4 wv4 = wr[q], b4 = bp[q];
            s += wv4.x*b4.x + wv4.y*b4.y + wv4.z*b4.z + wv4.w*b4.w;
        }
        s += __shfl_xor(s, 1);
        s += __shfl_xor(s, 2);
        if (part == 0) bvlG[i0 + r] = s;
    }
}

// ---------------- z: iv = 1/(4096 + (xs.h + c1)/512); partials of y = sum iv*xs, S0 = sum iv ----------------
__global__ __launch_bounds__(256) void z_kernel(const f16* __restrict__ xs_h,
    const float* __restrict__ hG, const float* __restrict__ c1G,
    float* __restrict__ partialY, float* __restrict__ partialS0)
{
    __shared__ float hs[512];
    __shared__ float yred[4][512];
    __shared__ float s0red[4];
    const int blk = blockIdx.x, t = threadIdx.x;
    const int b = blk >> 6, w = t >> 6, l = t & 63;
    hs[t] = hG[b*512 + t]; hs[t+256] = hG[b*512 + t + 256];
    __syncthreads();
    const float c1 = c1G[b];
    float hx[8];
    #pragma unroll
    for (int q = 0; q < 8; q++) hx[q] = hs[l*8+q];
    float yacc[8] = {0,0,0,0,0,0,0,0};
    float s0acc = 0.f;
    for (int it = 0; it < 16; it++) {
        int row = blk*64 + w*16 + it;
        f16x8 v = *(const f16x8*)(xs_h + (size_t)row*512 + l*8);
        float xf[8];
        #pragma unroll
        for (int q = 0; q < 8; q++) xf[q] = (float)v[q];
        float d = 0.f;
        #pragma unroll
        for (int q = 0; q < 8; q++) d += xf[q]*hx[q];
        #pragma unroll
        for (int m = 1; m < 64; m <<= 1) d += __shfl_xor(d, m);
        float z  = 4096.0f + (d + c1)*(1.0f/512.0f);
        float iv = 1.0f/z;
        s0acc += iv;
        #pragma unroll
        for (int q = 0; q < 8; q++) yacc[q] += iv*xf[q];
    }
    #pragma unroll
    for (int q = 0; q < 8; q++) yred[w][l*8+q] = yacc[q];
    if (l == 0) s0red[w] = s0acc;
    __syncthreads();
    #pragma unroll
    for (int k = 0; k < 2; k++) {
        int c = t + k*256;
        partialY[(size_t)blk*512 + c] = yred[0][c]+yred[1][c]+yred[2][c]+yred[3][c];
    }
    if (t == 0) partialS0[blk] = s0red[0]+s0red[1]+s0red[2]+s0red[3];
}

// ---------------- rs: rs[row] = S0 + (xs.u + c2)/512 ----------------
__global__ __launch_bounds__(256) void rs_kernel(const f16* __restrict__ xs_h,
    const float* __restrict__ uG, const float* __restrict__ c2G, const float* __restrict__ S0G,
    float* __restrict__ rsG)
{
    __shared__ float us[512];
    const int blk = blockIdx.x, t = threadIdx.x;
    const int b = blk >> 6, w = t >> 6, l = t & 63;
    us[t] = uG[b*512 + t]; us[t+256] = uG[b*512 + t + 256];
    __syncthreads();
    const float c2 = c2G[b], S0 = S0G[b];
    float ux[8];
    #pragma unroll
    for (int q = 0; q < 8; q++) ux[q] = us[l*8+q];
    for (int it = 0; it < 16; it++) {
        int row = blk*64 + w*16 + it;
        f16x8 v = *(const f16x8*)(xs_h + (size_t)row*512 + l*8);
        float d = 0.f;
        #pragma unroll
        for (int q = 0; q < 8; q++) d += (float)v[q]*ux[q];
        #pragma unroll
        for (int m = 1; m < 64; m <<= 1) d += __shfl_xor(d, m);
        if (l == 0) rsG[row] = S0 + (d + c2)*(1.0f/512.0f);
    }
}

// ---------------- vl_gemm: out = tanh(rs*(xs@Wvl^T + bvl) + bl) ----------------
__global__ __launch_bounds__(256, 2) void vl_gemm(const f16* __restrict__ A,
    const f16* __restrict__ Bt, const float* __restrict__ bvlG,
    const float* __restrict__ blG, const float* __restrict__ rsG,
    float* __restrict__ out)
{
    constexpr int K = 512;
    __shared__ f16 lA[128*32];
    __shared__ f16 lB[128*32];
    const int t = threadIdx.x;
    const int m0 = blockIdx.x*128, n0 = blockIdx.y*128;
    const int lane = t & 63, wid = t >> 6;
    const int wm = (wid & 1) << 6, wn = (wid >> 1) << 6;
    const int srow = t >> 2, skb = (t & 3) << 4;
    const long aoff0 = (long)(m0 + srow)*(K*2) + skb;
    const long aoff1 = aoff0 + 64L*(K*2);
    const long boff0 = (long)(n0 + srow)*(K*2) + skb;
    const long boff1 = boff0 + 64L*(K*2);
    char* ldsA = (char*)lA;
    char* ldsB = (char*)lB;
    const unsigned wbase = (unsigned)wid << 10;
    const char* Ab = (const char*)A;
    const char* Bb = (const char*)Bt;

    f32x4 acc[4][4] = {};
    const int ael = (wm + (lane & 15))*32 + ((lane >> 4) << 3);
    const int bel = (wn + (lane & 15))*32 + ((lane >> 4) << 3);

    for (int k0 = 0; k0 < K; k0 += 32) {
        __syncthreads();
        const long kb = (long)k0*2;
        gl2lds16(Ab + aoff0 + kb, ldsA + wbase);
        gl2lds16(Ab + aoff1 + kb, ldsA + 4096 + wbase);
        gl2lds16(Bb + boff0 + kb, ldsB + wbase);
        gl2lds16(Bb + boff1 + kb, ldsB + 4096 + wbase);
        __syncthreads();
        f16x8 af[4], bf[4];
        #pragma unroll
        for (int i = 0; i < 4; i++) af[i] = *(const f16x8*)(lA + ael + i*512);
        #pragma unroll
        for (int j = 0; j < 4; j++) bf[j] = *(const f16x8*)(lB + bel + j*512);
        #pragma unroll
        for (int i = 0; i < 4; i++)
            #pragma unroll
            for (int j = 0; j < 4; j++)
                acc[i][j] = __builtin_amdgcn_mfma_f32_16x16x32_f16(af[i], bf[j], acc[i][j], 0, 0, 0);
    }

    const int crb = m0 + wm + ((lane >> 4) << 2);
    const int ccb = n0 + wn + (lane & 15);
    #pragma unroll
    for (int i = 0; i < 4; i++) {
        float rsv[4];
        #pragma unroll
        for (int r = 0; r < 4; r++) rsv[r] = rsG[crb + i*16 + r];
        #pragma unroll
        for (int j = 0; j < 4; j++) {
            int c = ccb + j*16;
            float bb = bvlG[c], bo = blG[c];
            #pragma unroll
            for (int r = 0; r < 4; r++) {
                float yv = rsv[r]*(acc[i][j][r] + bb) + bo;
                float e2 = __expf(2.0f*yv);
                out[(size_t)(crb + i*16 + r)*512 + c] = 1.0f - 2.0f/(e2 + 1.0f);
            }
        }
    }
}

extern "C" void kernel_launch(void* const* d_in, const int* in_sizes, int n_in,
                              void* d_out, int out_size, void* d_ws, size_t ws_size,
                              hipStream_t stream)
{
    const float* xs = (const float*)d_in[0];
    const float* Wk = (const float*)d_in[1];
    const float* bk = (const float*)d_in[2];
    const float* Wq = (const float*)d_in[3];
    const float* bq = (const float*)d_in[4];
    const float* Wv = (const float*)d_in[5];
    const float* bv = (const float*)d_in[6];
    const float* Wl = (const float*)d_in[7];
    const float* bl = (const float*)d_in[8];
    float* out = (float*)d_out;

    char* w = (char*)d_ws;
    f16*   xs_h      = (f16*)w;    w += (size_t)M_*D_*2;
    f16*   WvlH      = (f16*)w;    w += (size_t)D_*D_*2;
    float* partialXS = (float*)w;  w += (size_t)256*512*4;
    float* partialY  = (float*)w;  w += (size_t)256*512*4;
    float* rsG       = (float*)w;  w += (size_t)M_*4;
    float* xsSum     = (float*)w;  w += 4*512*4;
    float* kSum      = (float*)w;  w += 4*512*4;
    float* hG        = (float*)w;  w += 4*512*4;
    float* yG        = (float*)w;  w += 4*512*4;
    float* qwG       = (float*)w;  w += 4*512*4;
    float* uG        = (float*)w;  w += 4*512*4;
    float* bvlG      = (float*)w;  w += 512*4;
    float* partialS0 = (float*)w;  w += 256*4;
    float* c1G       = (float*)w;  w += 4*4;
    float* c2G       = (float*)w;  w += 4*4;
    float* S0G       = (float*)w;  w += 4*4;
    if ((size_t)(w - (char*)d_ws) > ws_size) return;

    wvl_kernel<<<dim3(8,8), 256, 0, stream>>>(Wl, Wv, bv, WvlH, bvlG);
    prep_kernel<<<256, 256, 0, stream>>>(xs, xs_h, partialXS);
    red_kernel<<<8, 256, 0, stream>>>(partialXS, nullptr, xsSum, nullptr);
    mva_kernel<<<32, 256, 0, stream>>>(Wk, xsSum, bk, nullptr, kSum);
    mvb_kernel<<<8, 256, 0, stream>>>(Wq, kSum, bq, hG, c1G);
    z_kernel<<<256, 256, 0, stream>>>(xs_h, hG, c1G, partialY, partialS0);
    red_kernel<<<8, 256, 0, stream>>>(partialY, partialS0, yG, S0G);
    mva_kernel<<<32, 256, 0, stream>>>(Wq, yG, bq, S0G, qwG);
    mvb_kernel<<<8, 256, 0, stream>>>(Wk, qwG, bk, uG, c2G);
    rs_kernel<<<256, 256, 0, stream>>>(xs_h, uG, c2G, S0G, rsG);
    vl_gemm<<<dim3(128,4), 256, 0, stream>>>(xs_h, WvlH, bvlG, bl, rsG, out);
}

// Round 4
// 188.347 us; speedup vs baseline: 2.3778x; 1.0600x over previous
//
#include <hip/hip_runtime.h>
#include <cstdint>

#define B_ 4
#define S_ 4096
#define D_ 512
#define M_ (B_*S_)   // 16384 rows

typedef _Float16 f16;
typedef _Float16 f16x8 __attribute__((ext_vector_type(8)));
typedef _Float16 f16x4 __attribute__((ext_vector_type(4)));
typedef _Float16 f16x2 __attribute__((ext_vector_type(2)));
typedef float    f32x4 __attribute__((ext_vector_type(4)));

typedef __attribute__((address_space(1))) void* as1p;
typedef __attribute__((address_space(3))) void* as3p;

__device__ __forceinline__ void gl2lds16(const void* g, void* l) {
    __builtin_amdgcn_global_load_lds((as1p)g, (as3p)l, 16, 0, 0);
}

union f16pack { f16x8 v8; f16x2 v2[4]; };

// ---------------- wgemm: all weight-only precompute in ONE kernel ----------------
// z==0: Wvl = Wl@Wv (f16), bvl = Wl@bv (blocks y==0); block(0,0) zeros accumulators
// z==1: M[j][e] = sum_d Wk[d][j]*Wq[d][e]  (+ MT = M^T); t1=Wq^T bk (x==0), t2=Wk^T bq (y==0),
//       t12 = bk.bq (block(0,0))
__global__ __launch_bounds__(256) void wgemm_kernel(
    const float* __restrict__ Wl, const float* __restrict__ Wv, const float* __restrict__ bv,
    const float* __restrict__ Wk, const float* __restrict__ Wq,
    const float* __restrict__ bk, const float* __restrict__ bq,
    f16* __restrict__ WvlH, float* __restrict__ bvlG,
    float* __restrict__ M, float* __restrict__ MT,
    float* __restrict__ t1, float* __restrict__ t2, float* __restrict__ t12,
    float* __restrict__ xsSum, float* __restrict__ yG, float* __restrict__ S0G)
{
    __shared__ float As[32][68];
    __shared__ float Bs[32][68];
    const int t = threadIdx.x;
    const int which = blockIdx.z;
    const int i0 = blockIdx.x*64, j0 = blockIdx.y*64;
    const int tx = t & 15, ty = t >> 4;

    if (which == 0 && blockIdx.x == 0 && blockIdx.y == 0) {
        // zero global accumulators (stream-ordered before prep/z)
        for (int q = t; q < 2048; q += 256) { xsSum[q] = 0.f; yG[q] = 0.f; }
        if (t < 4) S0G[t] = 0.f;
    }

    float acc[4][4] = {};
    float t1acc = 0.f, t2acc = 0.f;
    for (int k0 = 0; k0 < 512; k0 += 32) {
        __syncthreads();
        if (which == 0) {
            int i = t >> 2, kq = (t & 3) * 8;
            float4 a0 = *(const float4*)(Wl + (size_t)(i0+i)*512 + k0 + kq);
            float4 a1 = *(const float4*)(Wl + (size_t)(i0+i)*512 + k0 + kq + 4);
            As[kq+0][i]=a0.x; As[kq+1][i]=a0.y; As[kq+2][i]=a0.z; As[kq+3][i]=a0.w;
            As[kq+4][i]=a1.x; As[kq+5][i]=a1.y; As[kq+6][i]=a1.z; As[kq+7][i]=a1.w;
            int m = t >> 3, jq = (t & 7) * 8;
            float4 b0 = *(const float4*)(Wv + (size_t)(k0+m)*512 + j0 + jq);
            float4 b1 = *(const float4*)(Wv + (size_t)(k0+m)*512 + j0 + jq + 4);
            *(float4*)&Bs[m][jq]   = b0;
            *(float4*)&Bs[m][jq+4] = b1;
        } else {
            int m = t >> 3, jq = (t & 7) * 8;
            float4 a0 = *(const float4*)(Wk + (size_t)(k0+m)*512 + i0 + jq);
            float4 a1 = *(const float4*)(Wk + (size_t)(k0+m)*512 + i0 + jq + 4);
            *(float4*)&As[m][jq]   = a0;
            *(float4*)&As[m][jq+4] = a1;
            float4 b0 = *(const float4*)(Wq + (size_t)(k0+m)*512 + j0 + jq);
            float4 b1 = *(const float4*)(Wq + (size_t)(k0+m)*512 + j0 + jq + 4);
            *(float4*)&Bs[m][jq]   = b0;
            *(float4*)&Bs[m][jq+4] = b1;
        }
        __syncthreads();
        #pragma unroll
        for (int m = 0; m < 32; m++) {
            float4 av = *(const float4*)&As[m][ty*4];
            float4 bw = *(const float4*)&Bs[m][tx*4];
            float ar[4] = {av.x,av.y,av.z,av.w};
            float br[4] = {bw.x,bw.y,bw.z,bw.w};
            #pragma unroll
            for (int r = 0; r < 4; r++)
                #pragma unroll
                for (int c = 0; c < 4; c++) acc[r][c] += ar[r]*br[c];
        }
        if (which == 1 && t < 64) {
            if (blockIdx.x == 0) {
                #pragma unroll 8
                for (int d = 0; d < 32; d++) t1acc += Bs[d][t] * bk[k0+d];
            }
            if (blockIdx.y == 0) {
                #pragma unroll 8
                for (int d = 0; d < 32; d++) t2acc += As[d][t] * bq[k0+d];
            }
        }
    }

    if (which == 0) {
        #pragma unroll
        for (int r = 0; r < 4; r++) {
            f16x4 o;
            #pragma unroll
            for (int c = 0; c < 4; c++) o[c] = (f16)acc[r][c];
            *(f16x4*)(WvlH + (size_t)(i0+ty*4+r)*512 + j0 + tx*4) = o;
        }
        if (blockIdx.y == 0) {
            int r = t >> 2, part = t & 3;
            const float4* wr = (const float4*)(Wl + (size_t)(i0+r)*512 + part*128);
            const float4* bp = (const float4*)(bv + part*128);
            float s = 0.f;
            #pragma unroll 8
            for (int q = 0; q < 32; q++) {
                float4 wv4 = wr[q], b4 = bp[q];
                s += wv4.x*b4.x + wv4.y*b4.y + wv4.z*b4.z + wv4.w*b4.w;
            }
            s += __shfl_xor(s, 1);
            s += __shfl_xor(s, 2);
            if (part == 0) bvlG[i0 + r] = s;
        }
    } else {
        #pragma unroll
        for (int r = 0; r < 4; r++) {
            float4 mv = make_float4(acc[r][0], acc[r][1], acc[r][2], acc[r][3]);
            *(float4*)(M + (size_t)(i0+ty*4+r)*512 + j0 + tx*4) = mv;
        }
        #pragma unroll
        for (int c = 0; c < 4; c++)
            #pragma unroll
            for (int r = 0; r < 4; r++)
                MT[(size_t)(j0+tx*4+c)*512 + i0 + ty*4 + r] = acc[r][c];
        if (blockIdx.x == 0 && t < 64) t1[j0 + t] = t1acc;
        if (blockIdx.y == 0 && t < 64) t2[i0 + t] = t2acc;
        if (blockIdx.x == 0 && blockIdx.y == 0 && t < 64) {
            float s = 0.f;
            #pragma unroll
            for (int q = 0; q < 8; q++) s += bk[t*8+q]*bq[t*8+q];
            #pragma unroll
            for (int m = 1; m < 64; m <<= 1) s += __shfl_xor(s, m);
            if (t == 0) *t12 = s;
        }
    }
}

// ---------------- prep: cast xs->f16 + atomic column sums into xsSum ----------------
__global__ __launch_bounds__(256) void prep_kernel(const float* __restrict__ xs,
    f16* __restrict__ xs_h, float* __restrict__ xsSum)
{
    __shared__ float red[4][512];
    const int t = threadIdx.x, blk = blockIdx.x;
    const int w = t >> 6, l = t & 63;
    const int col = l * 8;
    float acc[8] = {0,0,0,0,0,0,0,0};
    for (int c = 0; c < 16; c++) {
        int row = blk*64 + c*4 + w;
        const float4* p = (const float4*)(xs + (size_t)row*512 + col);
        float4 a = p[0], b = p[1];
        f16x8 o;
        o[0]=(f16)a.x; o[1]=(f16)a.y; o[2]=(f16)a.z; o[3]=(f16)a.w;
        o[4]=(f16)b.x; o[5]=(f16)b.y; o[6]=(f16)b.z; o[7]=(f16)b.w;
        *(f16x8*)(xs_h + (size_t)row*512 + col) = o;
        acc[0]+=a.x; acc[1]+=a.y; acc[2]+=a.z; acc[3]+=a.w;
        acc[4]+=b.x; acc[5]+=b.y; acc[6]+=b.z; acc[7]+=b.w;
    }
    #pragma unroll
    for (int q = 0; q < 8; q++) red[w][col+q] = acc[q];
    __syncthreads();
    const int b = blk >> 6;
    #pragma unroll
    for (int k = 0; k < 2; k++) {
        int c = t + k*256;
        atomicAdd(&xsSum[b*512 + c], red[0][c]+red[1][c]+red[2][c]+red[3][c]);
    }
}

// ---------------- mva: oput[b][j] = W[j,:].vin[b] + beta_b*bias2[j]  (+ f16 copy) ----------------
// block 32: cG[b] = bias3.vin[b] + beta_b * t12
__global__ __launch_bounds__(256) void mva_kernel(const float* __restrict__ W,
    const float* __restrict__ vin, const float* __restrict__ bias2,
    const float* __restrict__ bias3, const float* __restrict__ betaG,
    const float* __restrict__ t12G,
    float* __restrict__ oput, f16* __restrict__ oput_h, float* __restrict__ cG)
{
    const int t = threadIdx.x, w = t >> 6, l = t & 63;
    if (blockIdx.x == 32) {
        const float4* b4 = (const float4*)(bias3 + l*8);
        const float4* v4 = (const float4*)(vin + w*512 + l*8);
        float4 b0 = b4[0], b1 = b4[1], v0 = v4[0], v1 = v4[1];
        float s = b0.x*v0.x + b0.y*v0.y + b0.z*v0.z + b0.w*v0.w
                + b1.x*v1.x + b1.y*v1.y + b1.z*v1.z + b1.w*v1.w;
        #pragma unroll
        for (int m = 1; m < 64; m <<= 1) s += __shfl_xor(s, m);
        if (l == 0) {
            float beta = betaG ? betaG[w] : 4096.0f;
            cG[w] = s + beta * (*t12G);
        }
        return;
    }
    float vb[4][8];
    #pragma unroll
    for (int b = 0; b < 4; b++) {
        float4 p0 = *(const float4*)(vin + b*512 + l*8);
        float4 p1 = *(const float4*)(vin + b*512 + l*8 + 4);
        vb[b][0]=p0.x; vb[b][1]=p0.y; vb[b][2]=p0.z; vb[b][3]=p0.w;
        vb[b][4]=p1.x; vb[b][5]=p1.y; vb[b][6]=p1.z; vb[b][7]=p1.w;
    }
    const int r0 = blockIdx.x*16 + w*4;
    float res[4][4];
    #pragma unroll
    for (int r = 0; r < 4; r++) {
        const float4* wr = (const float4*)(W + (size_t)(r0+r)*512 + l*8);
        float4 a = wr[0], c = wr[1];
        float wv[8] = {a.x,a.y,a.z,a.w,c.x,c.y,c.z,c.w};
        #pragma unroll
        for (int b = 0; b < 4; b++) {
            float s = 0.f;
            #pragma unroll
            for (int q = 0; q < 8; q++) s += wv[q]*vb[b][q];
            res[r][b] = s;
        }
    }
    #pragma unroll
    for (int r = 0; r < 4; r++)
        #pragma unroll
        for (int b = 0; b < 4; b++)
            #pragma unroll
            for (int m = 1; m < 64; m <<= 1) res[r][b] += __shfl_xor(res[r][b], m);
    if (l < 4) {
        const float beta = betaG ? betaG[l] : 4096.0f;
        #pragma unroll
        for (int r = 0; r < 4; r++) {
            float val = res[r][l] + beta*bias2[r0 + r];
            oput[l*512 + r0 + r] = val;
            if (oput_h) oput_h[l*512 + r0 + r] = (f16)val;
        }
    }
}

// ---------------- z: iv = 1/(4096 + (xs.h + c1)/512); atomic y += iv*xs, S0 += iv ----------------
__global__ __launch_bounds__(256) void z_kernel(const f16* __restrict__ xs_h,
    const float* __restrict__ hG, const float* __restrict__ c1G,
    float* __restrict__ yG, float* __restrict__ S0G)
{
    __shared__ float hs[512];
    __shared__ float yred[4][512];
    __shared__ float s0red[4];
    const int blk = blockIdx.x, t = threadIdx.x;
    const int b = blk >> 6, w = t >> 6, l = t & 63;
    hs[t] = hG[b*512 + t]; hs[t+256] = hG[b*512 + t + 256];
    __syncthreads();
    const float c1 = c1G[b];
    float hx[8];
    #pragma unroll
    for (int q = 0; q < 8; q++) hx[q] = hs[l*8+q];
    float yacc[8] = {0,0,0,0,0,0,0,0};
    float s0acc = 0.f;
    for (int it = 0; it < 16; it++) {
        int row = blk*64 + w*16 + it;
        f16x8 v = *(const f16x8*)(xs_h + (size_t)row*512 + l*8);
        float xf[8];
        #pragma unroll
        for (int q = 0; q < 8; q++) xf[q] = (float)v[q];
        float d = 0.f;
        #pragma unroll
        for (int q = 0; q < 8; q++) d += xf[q]*hx[q];
        #pragma unroll
        for (int m = 1; m < 64; m <<= 1) d += __shfl_xor(d, m);
        float z  = 4096.0f + (d + c1)*(1.0f/512.0f);
        float iv = 1.0f/z;
        s0acc += iv;
        #pragma unroll
        for (int q = 0; q < 8; q++) yacc[q] += iv*xf[q];
    }
    #pragma unroll
    for (int q = 0; q < 8; q++) yred[w][l*8+q] = yacc[q];
    if (l == 0) s0red[w] = s0acc;
    __syncthreads();
    #pragma unroll
    for (int k = 0; k < 2; k++) {
        int c = t + k*256;
        atomicAdd(&yG[b*512 + c], yred[0][c]+yred[1][c]+yred[2][c]+yred[3][c]);
    }
    if (t == 0) atomicAdd(&S0G[b], s0red[0]+s0red[1]+s0red[2]+s0red[3]);
}

// ---------------- vl_gemm: out = tanh(rs*(xs@Wvl^T + bvl) + bl), rs fused via v_dot2 ----------------
__global__ __launch_bounds__(256, 2) void vl_gemm(const f16* __restrict__ A,
    const f16* __restrict__ Bt, const float* __restrict__ bvlG,
    const float* __restrict__ blG, const f16* __restrict__ uH,
    const float* __restrict__ c2G, const float* __restrict__ S0G,
    float* __restrict__ out)
{
    constexpr int K = 512;
    __shared__ f16 lA[128*32];
    __shared__ f16 lB[128*32];
    __shared__ float rsbuf[128];
    const int t = threadIdx.x;
    const int m0 = blockIdx.x*128, n0 = blockIdx.y*128;
    const int lane = t & 63, wid = t >> 6;
    const int wm = (wid & 1) << 6, wn = (wid >> 1) << 6;
    const int srow = t >> 2, skb = (t & 3) << 4;
    const long aoff0 = (long)(m0 + srow)*(K*2) + skb;
    const long aoff1 = aoff0 + 64L*(K*2);
    const long boff0 = (long)(n0 + srow)*(K*2) + skb;
    const long boff1 = boff0 + 64L*(K*2);
    char* ldsA = (char*)lA;
    char* ldsB = (char*)lB;
    const unsigned wbase = (unsigned)wid << 10;
    const char* Ab = (const char*)A;
    const char* Bb = (const char*)Bt;

    const int bat = blockIdx.x >> 5;          // 32 m-tiles per batch
    const f16* u = uH + bat*512;
    const int ku = (lane >> 4) << 3;

    f32x4 acc[4][4] = {};
    float racc[4] = {0.f,0.f,0.f,0.f};
    const int ael = (wm + (lane & 15))*32 + ku;
    const int bel = (wn + (lane & 15))*32 + ku;

    for (int k0 = 0; k0 < K; k0 += 32) {
        __syncthreads();
        const long kb = (long)k0*2;
        gl2lds16(Ab + aoff0 + kb, ldsA + wbase);
        gl2lds16(Ab + aoff1 + kb, ldsA + 4096 + wbase);
        gl2lds16(Bb + boff0 + kb, ldsB + wbase);
        gl2lds16(Bb + boff1 + kb, ldsB + 4096 + wbase);
        __syncthreads();
        f16x8 af[4], bf[4];
        #pragma unroll
        for (int i = 0; i < 4; i++) af[i] = *(const f16x8*)(lA + ael + i*512);
        #pragma unroll
        for (int j = 0; j < 4; j++) bf[j] = *(const f16x8*)(lB + bel + j*512);
        f16pack up; up.v8 = *(const f16x8*)(u + k0 + ku);
        #pragma unroll
        for (int i = 0; i < 4; i++) {
            f16pack ap; ap.v8 = af[i];
            #pragma unroll
            for (int q = 0; q < 4; q++)
                racc[i] = __builtin_amdgcn_fdot2(ap.v2[q], up.v2[q], racc[i], false);
        }
        #pragma unroll
        for (int i = 0; i < 4; i++)
            #pragma unroll
            for (int j = 0; j < 4; j++)
                acc[i][j] = __builtin_amdgcn_mfma_f32_16x16x32_f16(af[i], bf[j], acc[i][j], 0, 0, 0);
    }

    // finish rs: reduce partial k-slices across lane groups, stash in LDS
    #pragma unroll
    for (int i = 0; i < 4; i++) {
        racc[i] += __shfl_xor(racc[i], 16);
        racc[i] += __shfl_xor(racc[i], 32);
    }
    const float S0 = S0G[bat], c2 = c2G[bat];
    if (wid < 2 && lane < 16) {
        #pragma unroll
        for (int i = 0; i < 4; i++)
            rsbuf[wm + i*16 + lane] = S0 + (racc[i] + c2)*(1.0f/512.0f);
    }
    __syncthreads();

    const int crb = m0 + wm + ((lane >> 4) << 2);
    const int ccb = n0 + wn + (lane & 15);
    const int lrb = wm + ((lane >> 4) << 2);
    #pragma unroll
    for (int i = 0; i < 4; i++) {
        float rsv[4];
        #pragma unroll
        for (int r = 0; r < 4; r++) rsv[r] = rsbuf[lrb + i*16 + r];
        #pragma unroll
        for (int j = 0; j < 4; j++) {
            int c = ccb + j*16;
            float bb = bvlG[c], bo = blG[c];
            #pragma unroll
            for (int r = 0; r < 4; r++) {
                float yv = rsv[r]*(acc[i][j][r] + bb) + bo;
                float e2 = __expf(2.0f*yv);
                out[(size_t)(crb + i*16 + r)*512 + c] = 1.0f - 2.0f/(e2 + 1.0f);
            }
        }
    }
}

extern "C" void kernel_launch(void* const* d_in, const int* in_sizes, int n_in,
                              void* d_out, int out_size, void* d_ws, size_t ws_size,
                              hipStream_t stream)
{
    const float* xs = (const float*)d_in[0];
    const float* Wk = (const float*)d_in[1];
    const float* bk = (const float*)d_in[2];
    const float* Wq = (const float*)d_in[3];
    const float* bq = (const float*)d_in[4];
    const float* Wv = (const float*)d_in[5];
    const float* bv = (const float*)d_in[6];
    const float* Wl = (const float*)d_in[7];
    const float* bl = (const float*)d_in[8];
    float* out = (float*)d_out;

    char* w = (char*)d_ws;
    f16*   xs_h = (f16*)w;   w += (size_t)M_*D_*2;   // 16.8 MB
    f16*   WvlH = (f16*)w;   w += (size_t)D_*D_*2;   // 0.5 MB
    float* Mm   = (float*)w; w += (size_t)D_*D_*4;   // 1 MB
    float* MT   = (float*)w; w += (size_t)D_*D_*4;   // 1 MB
    f16*   uH   = (f16*)w;   w += (size_t)B_*D_*2;
    float* xsSum= (float*)w; w += (size_t)B_*D_*4;
    float* yG   = (float*)w; w += (size_t)B_*D_*4;
    float* hG   = (float*)w; w += (size_t)B_*D_*4;
    float* uG   = (float*)w; w += (size_t)B_*D_*4;
    float* t1   = (float*)w; w += (size_t)D_*4;
    float* t2   = (float*)w; w += (size_t)D_*4;
    float* bvlG = (float*)w; w += (size_t)D_*4;
    float* S0G  = (float*)w; w += 4*4;
    float* c1G  = (float*)w; w += 4*4;
    float* c2G  = (float*)w; w += 4*4;
    float* t12  = (float*)w; w += 4;
    if ((size_t)(w - (char*)d_ws) > ws_size) return;  // fail loudly

    wgemm_kernel<<<dim3(8,8,2), 256, 0, stream>>>(Wl, Wv, bv, Wk, Wq, bk, bq,
        WvlH, bvlG, Mm, MT, t1, t2, t12, xsSum, yG, S0G);
    prep_kernel<<<256, 256, 0, stream>>>(xs, xs_h, xsSum);
    mva_kernel<<<33, 256, 0, stream>>>(MT, xsSum, t1, t2, nullptr, t12, hG, nullptr, c1G);
    z_kernel<<<256, 256, 0, stream>>>(xs_h, hG, c1G, yG, S0G);
    mva_kernel<<<33, 256, 0, stream>>>(Mm, yG, t2, t1, S0G, t12, uG, uH, c2G);
    vl_gemm<<<dim3(128,4), 256, 0, stream>>>(xs_h, WvlH, bvlG, bl, uH, c2G, S0G, out);
}

// Round 6
// 158.329 us; speedup vs baseline: 2.8287x; 1.1896x over previous
//
#include <hip/hip_runtime.h>
#include <cstdint>

#define B_ 4
#define S_ 4096
#define D_ 512
#define M_ (B_*S_)   // 16384 rows

typedef _Float16 f16;
typedef _Float16 f16x8 __attribute__((ext_vector_type(8)));
typedef _Float16 f16x4 __attribute__((ext_vector_type(4)));
typedef _Float16 f16x2 __attribute__((ext_vector_type(2)));
typedef float    f32x4 __attribute__((ext_vector_type(4)));

typedef __attribute__((address_space(1))) void* as1p;
typedef __attribute__((address_space(3))) void* as3p;

__device__ __forceinline__ void gl2lds16(const void* g, void* l) {
    __builtin_amdgcn_global_load_lds((as1p)g, (as3p)l, 16, 0, 0);
}

union f16pack { f16x8 v8; f16x2 v2[4]; };

// ---------------- tr: z<3 transpose {Wv,Wk,Wq}->f16; z==3 cast Wl->f16 + zero accumulators ----
__global__ __launch_bounds__(256) void tr_kernel(
    const float* __restrict__ Wv, const float* __restrict__ Wk, const float* __restrict__ Wq,
    const float* __restrict__ Wl,
    f16* __restrict__ WvT, f16* __restrict__ WkT, f16* __restrict__ WqT, f16* __restrict__ WlH,
    float* __restrict__ xsSum, float* __restrict__ yG, float* __restrict__ S0G)
{
    const int t = threadIdx.x, z = blockIdx.z;
    if (z == 3) {
        const int blkLin = blockIdx.y*8 + blockIdx.x;
        const size_t base = (size_t)blkLin*4096 + t*16;
        const float4* s4 = (const float4*)(Wl + base);
        float4 a0 = s4[0], a1 = s4[1], a2 = s4[2], a3 = s4[3];
        f16x8 o0, o1;
        o0[0]=(f16)a0.x; o0[1]=(f16)a0.y; o0[2]=(f16)a0.z; o0[3]=(f16)a0.w;
        o0[4]=(f16)a1.x; o0[5]=(f16)a1.y; o0[6]=(f16)a1.z; o0[7]=(f16)a1.w;
        o1[0]=(f16)a2.x; o1[1]=(f16)a2.y; o1[2]=(f16)a2.z; o1[3]=(f16)a2.w;
        o1[4]=(f16)a3.x; o1[5]=(f16)a3.y; o1[6]=(f16)a3.z; o1[7]=(f16)a3.w;
        *(f16x8*)(WlH + base)     = o0;
        *(f16x8*)(WlH + base + 8) = o1;
        if (blockIdx.x == 0 && blockIdx.y == 0) {
            for (int q = t; q < 2048; q += 256) { xsSum[q] = 0.f; yG[q] = 0.f; }
            if (t < 4) S0G[t] = 0.f;
        }
        return;
    }
    // pad 68: row stride 272 B, float4 stores at byte offsets {0,64,128,192} stay 16B-aligned
    __shared__ float tile[64][68];
    const float* src = (z == 0) ? Wv : ((z == 1) ? Wk : Wq);
    f16* dst = (z == 0) ? WvT : ((z == 1) ? WkT : WqT);
    const int i0 = blockIdx.x*64, j0 = blockIdx.y*64;
    const int r = t >> 2, cpart = (t & 3)*16;
    {
        const float4* s4 = (const float4*)(src + (size_t)(i0 + r)*512 + j0 + cpart);
        float4 a0 = s4[0], a1 = s4[1], a2 = s4[2], a3 = s4[3];
        *(float4*)&tile[r][cpart]    = a0;
        *(float4*)&tile[r][cpart+4]  = a1;
        *(float4*)&tile[r][cpart+8]  = a2;
        *(float4*)&tile[r][cpart+12] = a3;
    }
    __syncthreads();
    const int c = t >> 2, rpart = (t & 3)*16;
    f16x8 o0, o1;
    #pragma unroll
    for (int q = 0; q < 8; q++) o0[q] = (f16)tile[rpart + q][c];
    #pragma unroll
    for (int q = 0; q < 8; q++) o1[q] = (f16)tile[rpart + 8 + q][c];
    *(f16x8*)(dst + (size_t)(j0 + c)*512 + i0 + rpart)     = o0;
    *(f16x8*)(dst + (size_t)(j0 + c)*512 + i0 + rpart + 8) = o1;
}

// ---------------- wmm: MFMA weight GEMMs ----------------
// z==0: Wvl[n][k] = sum_d WlH[n][d]*WvT[k][d] (f16 out); y==0 blocks: bvl = Wl@bv (fp32 read)
// z==1: M[j][e] = sum_d WkT[j][d]*WqT[e][d] (fp32 out M + MT);
//       x==0: t1[e] = WqT[e,:].bk ; y==0: t2[j] = WkT[j,:].bq ; (0,0): t12 = bk.bq
__global__ __launch_bounds__(256) void wmm_kernel(
    const f16* __restrict__ WlH, const f16* __restrict__ WvT,
    const f16* __restrict__ WkT, const f16* __restrict__ WqT,
    const float* __restrict__ Wl, const float* __restrict__ bv,
    const float* __restrict__ bk, const float* __restrict__ bq,
    f16* __restrict__ WvlH, float* __restrict__ bvlG,
    float* __restrict__ Mm, float* __restrict__ MT,
    float* __restrict__ t1, float* __restrict__ t2, float* __restrict__ t12)
{
    __shared__ f16 lA[64*32];
    __shared__ f16 lB[64*32];
    const int t = threadIdx.x, z = blockIdx.z;
    const int i0 = blockIdx.x*64, j0 = blockIdx.y*64;
    const int lane = t & 63, wid = t >> 6;
    const int wm = (wid & 1)*32, wn = (wid >> 1)*32;
    const f16* A = z ? WkT : WlH;
    const f16* B = z ? WqT : WvT;
    // 64-row tile, 64 B (32 f16) per row per k-chunk: thread t -> row t>>2, bytes (t&3)*16
    const int srow = t >> 2, skb = (t & 3) << 4;
    const long aoff = (long)(i0 + srow)*1024 + skb;
    const long boff = (long)(j0 + srow)*1024 + skb;
    const unsigned wbase = (unsigned)wid << 10;
    const bool doT1 = (z == 1) && (blockIdx.x == 0);
    const bool doT2 = (z == 1) && (blockIdx.y == 0);
    const int jj = t >> 2, kq = (t & 3)*8;

    f32x4 acc[2][2] = {};
    float t1a = 0.f, t2a = 0.f;
    const int ael = (wm + (lane & 15))*32 + ((lane >> 4) << 3);
    const int bel = (wn + (lane & 15))*32 + ((lane >> 4) << 3);

    for (int k0 = 0; k0 < 512; k0 += 32) {
        __syncthreads();
        gl2lds16((const char*)A + aoff + k0*2, (char*)lA + wbase);
        gl2lds16((const char*)B + boff + k0*2, (char*)lB + wbase);
        __syncthreads();
        f16x8 af[2], bf[2];
        af[0] = *(const f16x8*)(lA + ael);
        af[1] = *(const f16x8*)(lA + ael + 512);
        bf[0] = *(const f16x8*)(lB + bel);
        bf[1] = *(const f16x8*)(lB + bel + 512);
        #pragma unroll
        for (int i = 0; i < 2; i++)
            #pragma unroll
            for (int j = 0; j < 2; j++)
                acc[i][j] = __builtin_amdgcn_mfma_f32_16x16x32_f16(af[i], bf[j], acc[i][j], 0, 0, 0);
        if (doT1) {
            float4 b0 = *(const float4*)(bk + k0 + kq);
            float4 b1 = *(const float4*)(bk + k0 + kq + 4);
            float bb[8] = {b0.x,b0.y,b0.z,b0.w,b1.x,b1.y,b1.z,b1.w};
            #pragma unroll
            for (int q = 0; q < 8; q++) t1a += (float)lB[jj*32 + kq + q] * bb[q];
        }
        if (doT2) {
            float4 b0 = *(const float4*)(bq + k0 + kq);
            float4 b1 = *(const float4*)(bq + k0 + kq + 4);
            float bb[8] = {b0.x,b0.y,b0.z,b0.w,b1.x,b1.y,b1.z,b1.w};
            #pragma unroll
            for (int q = 0; q < 8; q++) t2a += (float)lA[jj*32 + kq + q] * bb[q];
        }
    }

    const int rb = wm + ((lane >> 4) << 2);
    const int cb = wn + (lane & 15);
    if (z == 0) {
        #pragma unroll
        for (int i = 0; i < 2; i++)
            #pragma unroll
            for (int j = 0; j < 2; j++)
                #pragma unroll
                for (int r = 0; r < 4; r++)
                    WvlH[(size_t)(i0 + rb + i*16 + r)*512 + j0 + cb + j*16] = (f16)acc[i][j][r];
        if (blockIdx.y == 0) {
            int r = t >> 2, part = t & 3;
            const float4* wr = (const float4*)(Wl + (size_t)(i0+r)*512 + part*128);
            const float4* bp = (const float4*)(bv + part*128);
            float s = 0.f;
            #pragma unroll 8
            for (int q = 0; q < 32; q++) {
                float4 wv4 = wr[q], b4 = bp[q];
                s += wv4.x*b4.x + wv4.y*b4.y + wv4.z*b4.z + wv4.w*b4.w;
            }
            s += __shfl_xor(s, 1);
            s += __shfl_xor(s, 2);
            if (part == 0) bvlG[i0 + r] = s;
        }
    } else {
        #pragma unroll
        for (int i = 0; i < 2; i++)
            #pragma unroll
            for (int j = 0; j < 2; j++)
                #pragma unroll
                for (int r = 0; r < 4; r++) {
                    float v = acc[i][j][r];
                    int row = i0 + rb + i*16 + r, col = j0 + cb + j*16;
                    Mm[(size_t)row*512 + col] = v;
                    MT[(size_t)col*512 + row] = v;
                }
        if (doT1) {
            t1a += __shfl_xor(t1a, 1);
            t1a += __shfl_xor(t1a, 2);
            if ((lane & 3) == 0) t1[j0 + jj] = t1a;
        }
        if (doT2) {
            t2a += __shfl_xor(t2a, 1);
            t2a += __shfl_xor(t2a, 2);
            if ((lane & 3) == 0) t2[i0 + jj] = t2a;
        }
        if (blockIdx.x == 0 && blockIdx.y == 0 && wid == 0) {
            float s = 0.f;
            #pragma unroll
            for (int q = 0; q < 8; q++) s += bk[lane + q*64]*bq[lane + q*64];
            #pragma unroll
            for (int m = 1; m < 64; m <<= 1) s += __shfl_xor(s, m);
            if (lane == 0) *t12 = s;
        }
    }
}

// ---------------- prep: cast xs->f16 + atomic column sums into xsSum ----------------
__global__ __launch_bounds__(256) void prep_kernel(const float* __restrict__ xs,
    f16* __restrict__ xs_h, float* __restrict__ xsSum)
{
    __shared__ float red[4][512];
    const int t = threadIdx.x, blk = blockIdx.x;
    const int w = t >> 6, l = t & 63;
    const int col = l * 8;
    float acc[8] = {0,0,0,0,0,0,0,0};
    for (int c = 0; c < 16; c++) {
        int row = blk*64 + c*4 + w;
        const float4* p = (const float4*)(xs + (size_t)row*512 + col);
        float4 a = p[0], b = p[1];
        f16x8 o;
        o[0]=(f16)a.x; o[1]=(f16)a.y; o[2]=(f16)a.z; o[3]=(f16)a.w;
        o[4]=(f16)b.x; o[5]=(f16)b.y; o[6]=(f16)b.z; o[7]=(f16)b.w;
        *(f16x8*)(xs_h + (size_t)row*512 + col) = o;
        acc[0]+=a.x; acc[1]+=a.y; acc[2]+=a.z; acc[3]+=a.w;
        acc[4]+=b.x; acc[5]+=b.y; acc[6]+=b.z; acc[7]+=b.w;
    }
    #pragma unroll
    for (int q = 0; q < 8; q++) red[w][col+q] = acc[q];
    __syncthreads();
    const int b = blk >> 6;
    #pragma unroll
    for (int k = 0; k < 2; k++) {
        int c = t + k*256;
        atomicAdd(&xsSum[b*512 + c], red[0][c]+red[1][c]+red[2][c]+red[3][c]);
    }
}

// ---------------- mva: oput[b][j] = W[j,:].vin[b] + beta_b*bias2[j]  (+ f16 copy) ----------------
// block 32: cG[b] = bias3.vin[b] + beta_b * t12
__global__ __launch_bounds__(256) void mva_kernel(const float* __restrict__ W,
    const float* __restrict__ vin, const float* __restrict__ bias2,
    const float* __restrict__ bias3, const float* __restrict__ betaG,
    const float* __restrict__ t12G,
    float* __restrict__ oput, f16* __restrict__ oput_h, float* __restrict__ cG)
{
    const int t = threadIdx.x, w = t >> 6, l = t & 63;
    if (blockIdx.x == 32) {
        const float4* b4 = (const float4*)(bias3 + l*8);
        const float4* v4 = (const float4*)(vin + w*512 + l*8);
        float4 b0 = b4[0], b1 = b4[1], v0 = v4[0], v1 = v4[1];
        float s = b0.x*v0.x + b0.y*v0.y + b0.z*v0.z + b0.w*v0.w
                + b1.x*v1.x + b1.y*v1.y + b1.z*v1.z + b1.w*v1.w;
        #pragma unroll
        for (int m = 1; m < 64; m <<= 1) s += __shfl_xor(s, m);
        if (l == 0) {
            float beta = betaG ? betaG[w] : 4096.0f;
            cG[w] = s + beta * (*t12G);
        }
        return;
    }
    float vb[4][8];
    #pragma unroll
    for (int b = 0; b < 4; b++) {
        float4 p0 = *(const float4*)(vin + b*512 + l*8);
        float4 p1 = *(const float4*)(vin + b*512 + l*8 + 4);
        vb[b][0]=p0.x; vb[b][1]=p0.y; vb[b][2]=p0.z; vb[b][3]=p0.w;
        vb[b][4]=p1.x; vb[b][5]=p1.y; vb[b][6]=p1.z; vb[b][7]=p1.w;
    }
    const int r0 = blockIdx.x*16 + w*4;
    float res[4][4];
    #pragma unroll
    for (int r = 0; r < 4; r++) {
        const float4* wr = (const float4*)(W + (size_t)(r0+r)*512 + l*8);
        float4 a = wr[0], c = wr[1];
        float wv[8] = {a.x,a.y,a.z,a.w,c.x,c.y,c.z,c.w};
        #pragma unroll
        for (int b = 0; b < 4; b++) {
            float s = 0.f;
            #pragma unroll
            for (int q = 0; q < 8; q++) s += wv[q]*vb[b][q];
            res[r][b] = s;
        }
    }
    #pragma unroll
    for (int r = 0; r < 4; r++)
        #pragma unroll
        for (int b = 0; b < 4; b++)
            #pragma unroll
            for (int m = 1; m < 64; m <<= 1) res[r][b] += __shfl_xor(res[r][b], m);
    if (l < 4) {
        const float beta = betaG ? betaG[l] : 4096.0f;
        #pragma unroll
        for (int r = 0; r < 4; r++) {
            float val = res[r][l] + beta*bias2[r0 + r];
            oput[l*512 + r0 + r] = val;
            if (oput_h) oput_h[l*512 + r0 + r] = (f16)val;
        }
    }
}

// ---------------- z: iv = 1/(4096 + (xs.h + c1)/512); atomic y += iv*xs, S0 += iv ----------------
__global__ __launch_bounds__(256) void z_kernel(const f16* __restrict__ xs_h,
    const float* __restrict__ hG, const float* __restrict__ c1G,
    float* __restrict__ yG, float* __restrict__ S0G)
{
    __shared__ float hs[512];
    __shared__ float yred[4][512];
    __shared__ float s0red[4];
    const int blk = blockIdx.x, t = threadIdx.x;
    const int b = blk >> 6, w = t >> 6, l = t & 63;
    hs[t] = hG[b*512 + t]; hs[t+256] = hG[b*512 + t + 256];
    __syncthreads();
    const float c1 = c1G[b];
    float hx[8];
    #pragma unroll
    for (int q = 0; q < 8; q++) hx[q] = hs[l*8+q];
    float yacc[8] = {0,0,0,0,0,0,0,0};
    float s0acc = 0.f;
    for (int it = 0; it < 16; it++) {
        int row = blk*64 + w*16 + it;
        f16x8 v = *(const f16x8*)(xs_h + (size_t)row*512 + l*8);
        float xf[8];
        #pragma unroll
        for (int q = 0; q < 8; q++) xf[q] = (float)v[q];
        float d = 0.f;
        #pragma unroll
        for (int q = 0; q < 8; q++) d += xf[q]*hx[q];
        #pragma unroll
        for (int m = 1; m < 64; m <<= 1) d += __shfl_xor(d, m);
        float z  = 4096.0f + (d + c1)*(1.0f/512.0f);
        float iv = 1.0f/z;
        s0acc += iv;
        #pragma unroll
        for (int q = 0; q < 8; q++) yacc[q] += iv*xf[q];
    }
    #pragma unroll
    for (int q = 0; q < 8; q++) yred[w][l*8+q] = yacc[q];
    if (l == 0) s0red[w] = s0acc;
    __syncthreads();
    #pragma unroll
    for (int k = 0; k < 2; k++) {
        int c = t + k*256;
        atomicAdd(&yG[b*512 + c], yred[0][c]+yred[1][c]+yred[2][c]+yred[3][c]);
    }
    if (t == 0) atomicAdd(&S0G[b], s0red[0]+s0red[1]+s0red[2]+s0red[3]);
}

// ---------------- vl_gemm: out = tanh(rs*(xs@Wvl^T + bvl) + bl), rs fused via v_dot2 ----------------
__global__ __launch_bounds__(256, 2) void vl_gemm(const f16* __restrict__ A,
    const f16* __restrict__ Bt, const float* __restrict__ bvlG,
    const float* __restrict__ blG, const f16* __restrict__ uH,
    const float* __restrict__ c2G, const float* __restrict__ S0G,
    float* __restrict__ out)
{
    constexpr int K = 512;
    __shared__ f16 lA[128*32];
    __shared__ f16 lB[128*32];
    __shared__ float rsbuf[128];
    const int t = threadIdx.x;
    const int m0 = blockIdx.x*128, n0 = blockIdx.y*128;
    const int lane = t & 63, wid = t >> 6;
    const int wm = (wid & 1) << 6, wn = (wid >> 1) << 6;
    const int srow = t >> 2, skb = (t & 3) << 4;
    const long aoff0 = (long)(m0 + srow)*(K*2) + skb;
    const long aoff1 = aoff0 + 64L*(K*2);
    const long boff0 = (long)(n0 + srow)*(K*2) + skb;
    const long boff1 = boff0 + 64L*(K*2);
    char* ldsA = (char*)lA;
    char* ldsB = (char*)lB;
    const unsigned wbase = (unsigned)wid << 10;
    const char* Ab = (const char*)A;
    const char* Bb = (const char*)Bt;

    const int bat = blockIdx.x >> 5;          // 32 m-tiles per batch
    const f16* u = uH + bat*512;
    const int ku = (lane >> 4) << 3;

    f32x4 acc[4][4] = {};
    float racc[4] = {0.f,0.f,0.f,0.f};
    const int ael = (wm + (lane & 15))*32 + ku;
    const int bel = (wn + (lane & 15))*32 + ku;

    for (int k0 = 0; k0 < K; k0 += 32) {
        __syncthreads();
        const long kb = (long)k0*2;
        gl2lds16(Ab + aoff0 + kb, ldsA + wbase);
        gl2lds16(Ab + aoff1 + kb, ldsA + 4096 + wbase);
        gl2lds16(Bb + boff0 + kb, ldsB + wbase);
        gl2lds16(Bb + boff1 + kb, ldsB + 4096 + wbase);
        __syncthreads();
        f16x8 af[4], bf[4];
        #pragma unroll
        for (int i = 0; i < 4; i++) af[i] = *(const f16x8*)(lA + ael + i*512);
        #pragma unroll
        for (int j = 0; j < 4; j++) bf[j] = *(const f16x8*)(lB + bel + j*512);
        f16pack up; up.v8 = *(const f16x8*)(u + k0 + ku);
        #pragma unroll
        for (int i = 0; i < 4; i++) {
            f16pack ap; ap.v8 = af[i];
            #pragma unroll
            for (int q = 0; q < 4; q++)
                racc[i] = __builtin_amdgcn_fdot2(ap.v2[q], up.v2[q], racc[i], false);
        }
        #pragma unroll
        for (int i = 0; i < 4; i++)
            #pragma unroll
            for (int j = 0; j < 4; j++)
                acc[i][j] = __builtin_amdgcn_mfma_f32_16x16x32_f16(af[i], bf[j], acc[i][j], 0, 0, 0);
    }

    #pragma unroll
    for (int i = 0; i < 4; i++) {
        racc[i] += __shfl_xor(racc[i], 16);
        racc[i] += __shfl_xor(racc[i], 32);
    }
    const float S0 = S0G[bat], c2 = c2G[bat];
    if (wid < 2 && lane < 16) {
        #pragma unroll
        for (int i = 0; i < 4; i++)
            rsbuf[wm + i*16 + lane] = S0 + (racc[i] + c2)*(1.0f/512.0f);
    }
    __syncthreads();

    const int crb = m0 + wm + ((lane >> 4) << 2);
    const int ccb = n0 + wn + (lane & 15);
    const int lrb = wm + ((lane >> 4) << 2);
    #pragma unroll
    for (int i = 0; i < 4; i++) {
        float rsv[4];
        #pragma unroll
        for (int r = 0; r < 4; r++) rsv[r] = rsbuf[lrb + i*16 + r];
        #pragma unroll
        for (int j = 0; j < 4; j++) {
            int c = ccb + j*16;
            float bb = bvlG[c], bo = blG[c];
            #pragma unroll
            for (int r = 0; r < 4; r++) {
                float yv = rsv[r]*(acc[i][j][r] + bb) + bo;
                float e2 = __expf(2.0f*yv);
                out[(size_t)(crb + i*16 + r)*512 + c] = 1.0f - 2.0f/(e2 + 1.0f);
            }
        }
    }
}

extern "C" void kernel_launch(void* const* d_in, const int* in_sizes, int n_in,
                              void* d_out, int out_size, void* d_ws, size_t ws_size,
                              hipStream_t stream)
{
    const float* xs = (const float*)d_in[0];
    const float* Wk = (const float*)d_in[1];
    const float* bk = (const float*)d_in[2];
    const float* Wq = (const float*)d_in[3];
    const float* bq = (const float*)d_in[4];
    const float* Wv = (const float*)d_in[5];
    const float* bv = (const float*)d_in[6];
    const float* Wl = (const float*)d_in[7];
    const float* bl = (const float*)d_in[8];
    float* out = (float*)d_out;

    char* w = (char*)d_ws;
    f16*   xs_h = (f16*)w;   w += (size_t)M_*D_*2;   // 16.8 MB
    f16*   WvlH = (f16*)w;   w += (size_t)D_*D_*2;
    f16*   WlH  = (f16*)w;   w += (size_t)D_*D_*2;
    f16*   WvT  = (f16*)w;   w += (size_t)D_*D_*2;
    f16*   WkT  = (f16*)w;   w += (size_t)D_*D_*2;
    f16*   WqT  = (f16*)w;   w += (size_t)D_*D_*2;
    float* Mm   = (float*)w; w += (size_t)D_*D_*4;   // 1 MB
    float* MT   = (float*)w; w += (size_t)D_*D_*4;   // 1 MB
    f16*   uH   = (f16*)w;   w += (size_t)B_*D_*2;
    float* xsSum= (float*)w; w += (size_t)B_*D_*4;
    float* yG   = (float*)w; w += (size_t)B_*D_*4;
    float* hG   = (float*)w; w += (size_t)B_*D_*4;
    float* uG   = (float*)w; w += (size_t)B_*D_*4;
    float* t1   = (float*)w; w += (size_t)D_*4;
    float* t2   = (float*)w; w += (size_t)D_*4;
    float* bvlG = (float*)w; w += (size_t)D_*4;
    float* S0G  = (float*)w; w += 4*4;
    float* c1G  = (float*)w; w += 4*4;
    float* c2G  = (float*)w; w += 4*4;
    float* t12  = (float*)w; w += 4;
    if ((size_t)(w - (char*)d_ws) > ws_size) return;  // fail loudly

    tr_kernel<<<dim3(8,8,4), 256, 0, stream>>>(Wv, Wk, Wq, Wl, WvT, WkT, WqT, WlH,
        xsSum, yG, S0G);
    wmm_kernel<<<dim3(8,8,2), 256, 0, stream>>>(WlH, WvT, WkT, WqT, Wl, bv, bk, bq,
        WvlH, bvlG, Mm, MT, t1, t2, t12);
    prep_kernel<<<256, 256, 0, stream>>>(xs, xs_h, xsSum);
    mva_kernel<<<33, 256, 0, stream>>>(MT, xsSum, t1, t2, nullptr, t12, hG, nullptr, c1G);
    z_kernel<<<256, 256, 0, stream>>>(xs_h, hG, c1G, yG, S0G);
    mva_kernel<<<33, 256, 0, stream>>>(Mm, yG, t2, t1, S0G, t12, uG, uH, c2G);
    vl_gemm<<<dim3(128,4), 256, 0, stream>>>(xs_h, WvlH, bvlG, bl, uH, c2G, S0G, out);
}